// Round 9
// baseline (35464.169 us; speedup 1.0000x reference)
//
#include <hip/hip_runtime.h>
#include <cstdint>

#define TT 256
#define HH 256
#define LL 3
#define NTH 512
#define SWG 8          // WGs per cluster
#define CLN 32         // clusters
#define RW 4           // rows per cluster
#define LN_EPS 1e-5f
#define ACTSTRIDE 16384 // floats per cluster in d_ws act region

// ---------------- helpers ----------------

__device__ __forceinline__ float fast_sigmoid(float x) {
    return 1.f / (1.f + __expf(-x));
}
__device__ __forceinline__ float fast_tanh(float x) {
    float xc = fminf(fmaxf(x, -15.f), 15.f);
    float e = __expf(2.f * xc);
    return 1.f - 2.f / (e + 1.f);
}
__device__ __forceinline__ float relu(float x) { return fmaxf(x, 0.f); }

// Dual-row (sum, sumsq) reduction. Thread (n=tid&255, p=tid>>8) owns rows
// p and p+2. Returns (sumA, sqA, sumB, sqB). scr: 32 floats.
__device__ __forceinline__ float4 rowsum4(float s0, float q0, float s1, float q1,
                                          float* scr, int tid) {
#pragma unroll
    for (int o = 32; o > 0; o >>= 1) {
        s0 += __shfl_down(s0, o); q0 += __shfl_down(q0, o);
        s1 += __shfl_down(s1, o); q1 += __shfl_down(q1, o);
    }
    int w = tid >> 6;
    if ((tid & 63) == 0) { scr[w*4] = s0; scr[w*4+1] = q0; scr[w*4+2] = s1; scr[w*4+3] = q1; }
    __syncthreads();
    int base = (tid >> 8) * 16;
    float sA = 0, qA = 0, sB = 0, qB = 0;
#pragma unroll
    for (int i = 0; i < 4; i++) {
        sA += scr[base + i*4];     qA += scr[base + i*4 + 1];
        sB += scr[base + i*4 + 2]; qB += scr[base + i*4 + 3];
    }
    __syncthreads();
    return make_float4(sA, qA, sB, qB);
}

// Head reduction: thread (mm=tid&127, row=tid>>7); row r spans waves 2r,2r+1.
__device__ __forceinline__ float2 red2head(float a, float b, float* scr, int tid) {
#pragma unroll
    for (int o = 32; o > 0; o >>= 1) {
        a += __shfl_down(a, o);
        b += __shfl_down(b, o);
    }
    int w = tid >> 6;
    if ((tid & 63) == 0) { scr[w] = a; scr[8 + w] = b; }
    __syncthreads();
    int r = tid >> 7;
    float2 out = make_float2(scr[2*r] + scr[2*r+1], scr[8+2*r] + scr[8+2*r+1]);
    __syncthreads();
    return out;
}

__device__ __forceinline__ void fma16(float4 w, float4 x,
                                      float4& a0, float4& a1, float4& a2, float4& a3) {
    a0.x = fmaf(w.x, x.x, a0.x); a0.y = fmaf(w.y, x.x, a0.y);
    a0.z = fmaf(w.z, x.x, a0.z); a0.w = fmaf(w.w, x.x, a0.w);
    a1.x = fmaf(w.x, x.y, a1.x); a1.y = fmaf(w.y, x.y, a1.y);
    a1.z = fmaf(w.z, x.y, a1.z); a1.w = fmaf(w.w, x.y, a1.w);
    a2.x = fmaf(w.x, x.z, a2.x); a2.y = fmaf(w.y, x.z, a2.y);
    a2.z = fmaf(w.z, x.z, a2.z); a2.w = fmaf(w.w, x.z, a2.w);
    a3.x = fmaf(w.x, x.w, a3.x); a3.y = fmaf(w.y, x.w, a3.y);
    a3.z = fmaf(w.z, x.w, a3.z); a3.w = fmaf(w.w, x.w, a3.w);
}

// ---------------- main kernel ----------------

struct Args {
    const float *params, *disp;
    const float *embed_b, *embed_g, *embed_beta;
    const float *skip_b;
    const float *gates_b;
    const float *inln_g, *inln_b, *hln_g, *hln_b, *sln_g, *sln_b;
    const float *ab1, *aw2, *ab2;
    const float *rb1, *rb2, *rln_g, *rln_b;
    const float *ob1, *oln_g, *oln_b, *ow2, *ob2;
    const float *gw, *a1w, *r1w, *r2w, *ew, *sw, *o1w;
    float* out;
    float* act;   // cluster activation buffers
    int* bar;     // per-member flags, 16-int stride, 128 ints per cluster
};

__global__ __launch_bounds__(NTH) void xlstm_kernel(Args A) {
    const int tid = threadIdx.x;
    const int cid = blockIdx.x & 31;   // cluster id; members share XCD (blockIdx%8)
    const int m   = blockIdx.x >> 5;   // member 0..7
    const int n   = tid & 255;
    const int p   = tid >> 8;          // 0/1 -> rows p, p+2
    const int rA = p, rB = p + 2;

    float* gatesB = A.act + (size_t)cid * ACTSTRIDE;   // [4][1024]
    float* a1B  = gatesB + 4096;                       // [8][4] imp partials
    float* r2P  = gatesB + 4224;                       // [8][4][256] r2 partials
    float* o1B  = gatesB + 12416;                      // [2][4][128] (parity slots)
    int* myflag = A.bar + cid * 128 + m * 16;

    // LDS. P4 planes: [row][kg][j], plane stride PLx (padded) in float4 units.
    __shared__ __align__(16) float4 P4[2064];     // 33 KB partials
    __shared__ __align__(16) float4 xnhnT[512];
    __shared__ __align__(16) float4 cT4[256];
    __shared__ __align__(16) float4 hT4[256];
    __shared__ __align__(16) float4 xT4[256];
    __shared__ __align__(16) float4 skT4[128];
    __shared__ __align__(16) float4 r1locT[64];   // member's r1 slice, [local_k][row]
    __shared__ float xtT[17 * 4];
    __shared__ float scr[64];

    float x2[2] = {0.f, 0.f};
    float h2[LL][2] = {{0.f,0.f},{0.f,0.f},{0.f,0.f}};
    float c2[LL][2] = {{0.f,0.f},{0.f,0.f},{0.f,0.f}};

    int ep = 0;
    auto csig = [&]() {
        ep++;
        __syncthreads();   // all WG writes done before signal
        if (tid == 0)
            __hip_atomic_store(myflag, ep, __ATOMIC_RELEASE, __HIP_MEMORY_SCOPE_AGENT);
    };
    auto cwait = [&]() {
        if (tid < SWG) {
            const int* f = A.bar + cid * 128 + tid * 16;
            while (__hip_atomic_load(f, __ATOMIC_ACQUIRE, __HIP_MEMORY_SCOPE_AGENT) < ep)
                __builtin_amdgcn_s_sleep(2);
        }
        __syncthreads();
    };

    if (tid < 64) {
        int k = tid >> 2, rr = tid & 3;
        xtT[(1 + k) * 4 + rr] = A.params[(RW * cid + rr) * 16 + k];
    }
    __syncthreads();

    for (int t = 0; t < TT; t++) {
        if (tid < 4) xtT[tid] = A.disp[(RW * cid + tid) * TT + t];
        __syncthreads();

        // ---- embed + skip (redundant in every member) ----
        float e0 = A.embed_b[n], e1 = e0;
#pragma unroll 4
        for (int k = 0; k < 17; k++) {
            float w = A.ew[k * 256 + n];
            e0 = fmaf(w, xtT[k * 4 + rA], e0);
            e1 = fmaf(w, xtT[k * 4 + rB], e1);
        }
        {
            int mm = tid & 127, q = tid >> 7;
            float s = A.skip_b[mm];
#pragma unroll 4
            for (int k = 0; k < 17; k++) s = fmaf(A.sw[k * 128 + mm], xtT[k * 4 + q], s);
            ((float*)&skT4[mm])[q] = relu(s);
        }
        float4 rs = rowsum4(e0, e0 * e0, e1, e1 * e1, scr, tid);
        {
            float mu = rs.x * (1.f/HH), inv = rsqrtf(rs.y * (1.f/HH) - mu*mu + LN_EPS);
            x2[0] = relu((e0 - mu) * inv * A.embed_g[n] + A.embed_beta[n]);
            mu = rs.z * (1.f/HH); inv = rsqrtf(rs.w * (1.f/HH) - mu*mu + LN_EPS);
            x2[1] = relu((e1 - mu) * inv * A.embed_g[n] + A.embed_beta[n]);
        }

#pragma unroll 1
        for (int l = 0; l < LL; l++) {
            // ---- phase A (redundant): xn, hn, stage cT ----
            rs = rowsum4(x2[0], x2[0]*x2[0], x2[1], x2[1]*x2[1], scr, tid);
            {
                const float* g = A.inln_g + l*HH; const float* b = A.inln_b + l*HH;
                float mu = rs.x*(1.f/HH), inv = rsqrtf(rs.y*(1.f/HH) - mu*mu + LN_EPS);
                ((float*)&xnhnT[n])[rA] = (x2[0] - mu) * inv * g[n] + b[n];
                mu = rs.z*(1.f/HH); inv = rsqrtf(rs.w*(1.f/HH) - mu*mu + LN_EPS);
                ((float*)&xnhnT[n])[rB] = (x2[1] - mu) * inv * g[n] + b[n];
            }
            float hA = h2[l][0], hB = h2[l][1];
            rs = rowsum4(hA, hA*hA, hB, hB*hB, scr, tid);
            {
                const float* g = A.hln_g + l*HH; const float* b = A.hln_b + l*HH;
                float mu = rs.x*(1.f/HH), inv = rsqrtf(rs.y*(1.f/HH) - mu*mu + LN_EPS);
                ((float*)&xnhnT[256 + n])[rA] = (hA - mu) * inv * g[n] + b[n];
                mu = rs.z*(1.f/HH); inv = rsqrtf(rs.w*(1.f/HH) - mu*mu + LN_EPS);
                ((float*)&xnhnT[256 + n])[rB] = (hB - mu) * inv * g[n] + b[n];
            }
            ((float*)&cT4[n])[rA] = c2[l][0];
            ((float*)&cT4[n])[rB] = c2[l][1];
            __syncthreads();

            // ---- MV1: gates N-slice (K=512, 32 f4-cols). KG=16, PL=516 ----
            {
                int j = tid & 31, kg = tid >> 5;
                const float4* Wq = (const float4*)A.gw + (size_t)l*512*256 + (m*32 + j);
                float4 a0={0,0,0,0}, a1v={0,0,0,0}, a2={0,0,0,0}, a3={0,0,0,0};
                int k0 = kg * 32;
#pragma unroll 8
                for (int kk = 0; kk < 32; kk++) {
                    int k = k0 + kk;
                    fma16(Wq[(size_t)k * 256], xnhnT[k], a0, a1v, a2, a3);
                }
                int b = kg*32 + j;
                P4[b] = a0; P4[516 + b] = a1v; P4[2*516 + b] = a2; P4[3*516 + b] = a3;
            }
            __syncthreads();
            if (tid < 128) {
                int j2 = tid >> 2, row = tid & 3;
                float4 s = {0,0,0,0};
#pragma unroll
                for (int kg = 0; kg < 16; kg++) {
                    float4 v = P4[row*516 + kg*32 + j2];
                    s.x += v.x; s.y += v.y; s.z += v.z; s.w += v.w;
                }
                ((float4*)(gatesB + row*1024 + m*128))[j2] = s;
            }
            __syncthreads();
            // ---- MV1b: a1 N-slice (K=256, 8 f4-cols). KG=32, PL=260 ----
            if (tid < 256) {
                int j = tid & 7, kg = tid >> 3;
                const float4* Wq = (const float4*)A.a1w + (size_t)l*256*64 + (m*8 + j);
                float4 a0={0,0,0,0}, a1v={0,0,0,0}, a2={0,0,0,0}, a3={0,0,0,0};
                int k0 = kg * 8;
#pragma unroll
                for (int kk = 0; kk < 8; kk++) {
                    int k = k0 + kk;
                    fma16(Wq[(size_t)k * 64], cT4[k], a0, a1v, a2, a3);
                }
                int b = kg*8 + j;
                P4[b] = a0; P4[260 + b] = a1v; P4[2*260 + b] = a2; P4[3*260 + b] = a3;
            }
            __syncthreads();
            if (tid < 32) {
                int j2 = tid >> 2, row = tid & 3;
                float4 s = {0,0,0,0};
#pragma unroll
                for (int kg = 0; kg < 32; kg++) {
                    float4 v = P4[row*260 + kg*8 + j2];
                    s.x += v.x; s.y += v.y; s.z += v.z; s.w += v.w;
                }
                const float* ab1p = A.ab1 + l*HH + m*32 + j2*4;
                const float* aw2p = A.aw2 + l*HH + m*32 + j2*4;
                float d = fast_tanh(s.x + ab1p[0]) * aw2p[0]
                        + fast_tanh(s.y + ab1p[1]) * aw2p[1]
                        + fast_tanh(s.z + ab1p[2]) * aw2p[2]
                        + fast_tanh(s.w + ab1p[3]) * aw2p[3];
                scr[tid] = d;
            }
            __syncthreads();
            if (tid < 4) {
                float s = 0.f;
#pragma unroll
                for (int j2 = 0; j2 < 8; j2++) s += scr[j2*4 + tid];
                a1B[m*4 + tid] = s;
            }
            csig(); cwait();   // B1: gates + a1 partials visible

            // ---- phase B (redundant): imp, c, h ----
            float imp0, imp1;
            {
                float sA = A.ab2[l], sB = A.ab2[l];
#pragma unroll
                for (int mm = 0; mm < SWG; mm++) { sA += a1B[mm*4 + rA]; sB += a1B[mm*4 + rB]; }
                imp0 = fast_sigmoid(sA); imp1 = fast_sigmoid(sB);
            }
            const float* gb = A.gates_b + l*1024;
            float craw0, craw1, og0, og1;
            {
                const float* go = gatesB + rA*1024;
                float ii = fast_sigmoid(go[n] + gb[n]);
                float ff = fast_sigmoid(go[256+n] + gb[256+n]);
                float gg = fast_tanh(go[512+n] + gb[512+n]);
                og0 = fast_sigmoid(go[768+n] + gb[768+n]);
                craw0 = (ff * c2[l][0] + ii * gg) * imp0;
            }
            {
                const float* go = gatesB + rB*1024;
                float ii = fast_sigmoid(go[n] + gb[n]);
                float ff = fast_sigmoid(go[256+n] + gb[256+n]);
                float gg = fast_tanh(go[512+n] + gb[512+n]);
                og1 = fast_sigmoid(go[768+n] + gb[768+n]);
                craw1 = (ff * c2[l][1] + ii * gg) * imp1;
            }
            rs = rowsum4(craw0, craw0*craw0, craw1, craw1*craw1, scr, tid);
            {
                const float* g = A.sln_g + l*HH; const float* b = A.sln_b + l*HH;
                float mu = rs.x*(1.f/HH), inv = rsqrtf(rs.y*(1.f/HH) - mu*mu + LN_EPS);
                float cn = (craw0 - mu) * inv * g[n] + b[n];
                c2[l][0] = cn; float hh = og0 * fast_tanh(cn);
                h2[l][0] = hh; ((float*)&hT4[n])[rA] = hh;
                mu = rs.z*(1.f/HH); inv = rsqrtf(rs.w*(1.f/HH) - mu*mu + LN_EPS);
                cn = (craw1 - mu) * inv * g[n] + b[n];
                c2[l][1] = cn; hh = og1 * fast_tanh(cn);
                h2[l][1] = hh; ((float*)&hT4[n])[rB] = hh;
            }
            __syncthreads();

            // ---- MV2: r1 N-slice (K=256, 16 f4-cols). KG=32, PL=516 ----
            {
                int j = tid & 15, kg = tid >> 4;
                const float4* Wq = (const float4*)A.r1w + (size_t)l*256*128 + (m*16 + j);
                float4 a0={0,0,0,0}, a1v={0,0,0,0}, a2={0,0,0,0}, a3={0,0,0,0};
                int k0 = kg * 8;
#pragma unroll
                for (int kk = 0; kk < 8; kk++) {
                    int k = k0 + kk;
                    fma16(Wq[(size_t)k * 128], hT4[k], a0, a1v, a2, a3);
                }
                int b = kg*16 + j;
                P4[b] = a0; P4[516 + b] = a1v; P4[2*516 + b] = a2; P4[3*516 + b] = a3;
            }
            __syncthreads();
            if (tid < 64) {
                int j2 = tid >> 2, row = tid & 3;
                float4 s = {0,0,0,0};
#pragma unroll
                for (int kg = 0; kg < 32; kg++) {
                    float4 v = P4[row*516 + kg*16 + j2];
                    s.x += v.x; s.y += v.y; s.z += v.z; s.w += v.w;
                }
                const float* rb1p = A.rb1 + l*512 + m*64 + j2*4;
                ((float*)&r1locT[j2*4 + 0])[row] = relu(s.x + rb1p[0]);
                ((float*)&r1locT[j2*4 + 1])[row] = relu(s.y + rb1p[1]);
                ((float*)&r1locT[j2*4 + 2])[row] = relu(s.z + rb1p[2]);
                ((float*)&r1locT[j2*4 + 3])[row] = relu(s.w + rb1p[3]);
            }
            __syncthreads();

            // ---- MV3: r2 K-slice (rows m*64..m*64+63, all 64 f4-cols).
            //      KG=8, JJ=64, PL=516. Uses ONLY local r1 slice -> no barrier.
            {
                int j = tid & 63, kg = tid >> 6;
                const float4* Wq = (const float4*)A.r2w + (size_t)l*512*64
                                   + (size_t)(m*64) * 64 + j;
                float4 a0={0,0,0,0}, a1v={0,0,0,0}, a2={0,0,0,0}, a3={0,0,0,0};
                int k0 = kg * 8;
#pragma unroll
                for (int kk = 0; kk < 8; kk++) {
                    int lk = k0 + kk;
                    fma16(Wq[(size_t)lk * 64], r1locT[lk], a0, a1v, a2, a3);
                }
                int b = kg*64 + j;
                P4[b] = a0; P4[516 + b] = a1v; P4[2*516 + b] = a2; P4[3*516 + b] = a3;
            }
            __syncthreads();
            {
                int j2 = tid >> 2, row = tid & 3;     // j2 0..63 over 256 threads
                if (tid < 256) {
                    float4 s = {0,0,0,0};
#pragma unroll
                    for (int kg = 0; kg < 8; kg++) {
                        float4 v = P4[row*516 + kg*64 + j2];
                        s.x += v.x; s.y += v.y; s.z += v.z; s.w += v.w;
                    }
                    ((float4*)(r2P + m*1024 + row*256))[j2] = s;
                }
            }
            csig(); cwait();   // B2: r2 partials visible

            // ---- phase C (redundant): x = LN(sum r2 partials + rb2 + h) + res ----
            const float* rb2p = A.rb2 + l*HH;
            float s0 = rb2p[n] + h2[l][0];
            float s1 = rb2p[n] + h2[l][1];
#pragma unroll
            for (int mm = 0; mm < SWG; mm++) {
                s0 += r2P[mm*1024 + rA*256 + n];
                s1 += r2P[mm*1024 + rB*256 + n];
            }
            rs = rowsum4(s0, s0*s0, s1, s1*s1, scr, tid);
            {
                const float* g = A.rln_g + l*HH; const float* b = A.rln_b + l*HH;
                float mu = rs.x*(1.f/HH), inv = rsqrtf(rs.y*(1.f/HH) - mu*mu + LN_EPS);
                x2[0] = (s0 - mu) * inv * g[n] + b[n] + x2[0];
                mu = rs.z*(1.f/HH); inv = rsqrtf(rs.w*(1.f/HH) - mu*mu + LN_EPS);
                x2[1] = (s1 - mu) * inv * g[n] + b[n] + x2[1];
            }
        }   // layers

        // ---- head: o1 N-slice (K=384, 4 f4-cols). KG=128, PL=516 ----
        ((float*)&xT4[n])[rA] = x2[0];
        ((float*)&xT4[n])[rB] = x2[1];
        __syncthreads();
        {
            int j = tid & 3, kg = tid >> 2;
            const float4* Wq = (const float4*)A.o1w + (m*4 + j);
            float4 a0={0,0,0,0}, a1v={0,0,0,0}, a2={0,0,0,0}, a3={0,0,0,0};
            int k0 = kg * 3;
#pragma unroll
            for (int kk = 0; kk < 3; kk++) {
                int k = k0 + kk;
                float4 x = (k < 256) ? xT4[k] : skT4[k - 256];
                fma16(Wq[(size_t)k * 32], x, a0, a1v, a2, a3);
            }
            int b = kg*4 + j;
            P4[b] = a0; P4[516 + b] = a1v; P4[2*516 + b] = a2; P4[3*516 + b] = a3;
        }
        __syncthreads();
        float* o1S = o1B + (t & 1) * 512;
        if (tid < 16) {
            int j2 = tid >> 2, row = tid & 3;
            float4 s = {0,0,0,0};
#pragma unroll
            for (int kg = 0; kg < 128; kg++) {
                float4 v = P4[row*516 + kg*4 + j2];
                s.x += v.x; s.y += v.y; s.z += v.z; s.w += v.w;
            }
            ((float4*)(o1S + row*128 + m*16))[j2] = s;
        }
        csig();            // head partials signaled by all members
        if (m == 0) {
            cwait();       // only m0 consumes o1
            int mm = tid & 127, row = tid >> 7;
            float v = o1S[row*128 + mm] + A.ob1[mm];
            float2 f2 = red2head(v, v * v, scr, tid);
            float mu = f2.x * (1.f/128.f);
            float inv = rsqrtf(f2.y * (1.f/128.f) - mu*mu + LN_EPS);
            float contrib = relu((v - mu) * inv * A.oln_g[mm] + A.oln_b[mm]) * A.ow2[mm];
            f2 = red2head(contrib, 0.f, scr, tid);
            if (mm == 0) A.out[(RW*cid + row) * TT + t] = f2.x + A.ob2[0];
        }
        __syncthreads();   // protect LDS for next step
    }
}

// ---------------- launch ----------------

extern "C" void kernel_launch(void* const* d_in, const int* in_sizes, int n_in,
                              void* d_out, int out_size, void* d_ws, size_t ws_size,
                              hipStream_t stream) {
    // zero per-member flag region (32 clusters x 128 ints)
    hipMemsetAsync(d_ws, 0, CLN * 128 * sizeof(int), stream);

    Args A;
    A.params     = (const float*)d_in[0];
    A.disp       = (const float*)d_in[1];
    A.ew         = (const float*)d_in[2];
    A.embed_b    = (const float*)d_in[3];
    A.embed_g    = (const float*)d_in[4];
    A.embed_beta = (const float*)d_in[5];
    A.sw         = (const float*)d_in[6];
    A.skip_b     = (const float*)d_in[7];
    A.gw         = (const float*)d_in[8];
    A.gates_b    = (const float*)d_in[9];
    A.inln_g     = (const float*)d_in[10];
    A.inln_b     = (const float*)d_in[11];
    A.hln_g      = (const float*)d_in[12];
    A.hln_b      = (const float*)d_in[13];
    A.sln_g      = (const float*)d_in[14];
    A.sln_b      = (const float*)d_in[15];
    A.a1w        = (const float*)d_in[16];
    A.ab1        = (const float*)d_in[17];
    A.aw2        = (const float*)d_in[18];
    A.ab2        = (const float*)d_in[19];
    A.r1w        = (const float*)d_in[20];
    A.rb1        = (const float*)d_in[21];
    A.r2w        = (const float*)d_in[22];
    A.rb2        = (const float*)d_in[23];
    A.rln_g      = (const float*)d_in[24];
    A.rln_b      = (const float*)d_in[25];
    A.o1w        = (const float*)d_in[26];
    A.ob1        = (const float*)d_in[27];
    A.oln_g      = (const float*)d_in[28];
    A.oln_b      = (const float*)d_in[29];
    A.ow2        = (const float*)d_in[30];
    A.ob2        = (const float*)d_in[31];
    A.out        = (float*)d_out;
    A.bar        = (int*)d_ws;
    A.act        = (float*)d_ws + CLN * 128;

    xlstm_kernel<<<CLN * SWG, NTH, 0, stream>>>(A);
}

// Round 10
// 31791.943 us; speedup vs baseline: 1.1155x; 1.1155x over previous
//
#include <hip/hip_runtime.h>
#include <cstdint>

#define TT 256
#define HH 256
#define LL 3
#define NTH 512
#define SWG 8          // WGs per cluster
#define CLN 32         // clusters
#define RW 4           // rows per cluster
#define LN_EPS 1e-5f
#define ACTSTRIDE 16384 // floats per cluster in d_ws act region

// ---------------- helpers ----------------

__device__ __forceinline__ float fast_sigmoid(float x) {
    return 1.f / (1.f + __expf(-x));
}
__device__ __forceinline__ float fast_tanh(float x) {
    float xc = fminf(fmaxf(x, -15.f), 15.f);
    float e = __expf(2.f * xc);
    return 1.f - 2.f / (e + 1.f);
}
__device__ __forceinline__ float relu(float x) { return fmaxf(x, 0.f); }

// Dual-row (sum, sumsq) reduction. Thread (n=tid&255, p=tid>>8) owns rows
// p and p+2. Returns (sumA, sqA, sumB, sqB). scr: 32 floats.
__device__ __forceinline__ float4 rowsum4(float s0, float q0, float s1, float q1,
                                          float* scr, int tid) {
#pragma unroll
    for (int o = 32; o > 0; o >>= 1) {
        s0 += __shfl_down(s0, o); q0 += __shfl_down(q0, o);
        s1 += __shfl_down(s1, o); q1 += __shfl_down(q1, o);
    }
    int w = tid >> 6;
    if ((tid & 63) == 0) { scr[w*4] = s0; scr[w*4+1] = q0; scr[w*4+2] = s1; scr[w*4+3] = q1; }
    __syncthreads();
    int base = (tid >> 8) * 16;
    float sA = 0, qA = 0, sB = 0, qB = 0;
#pragma unroll
    for (int i = 0; i < 4; i++) {
        sA += scr[base + i*4];     qA += scr[base + i*4 + 1];
        sB += scr[base + i*4 + 2]; qB += scr[base + i*4 + 3];
    }
    __syncthreads();
    return make_float4(sA, qA, sB, qB);
}

// Head reduction: thread (mm=tid&127, row=tid>>7); row r spans waves 2r,2r+1.
__device__ __forceinline__ float2 red2head(float a, float b, float* scr, int tid) {
#pragma unroll
    for (int o = 32; o > 0; o >>= 1) {
        a += __shfl_down(a, o);
        b += __shfl_down(b, o);
    }
    int w = tid >> 6;
    if ((tid & 63) == 0) { scr[w] = a; scr[8 + w] = b; }
    __syncthreads();
    int r = tid >> 7;
    float2 out = make_float2(scr[2*r] + scr[2*r+1], scr[8+2*r] + scr[8+2*r+1]);
    __syncthreads();
    return out;
}

__device__ __forceinline__ void fma16(float4 w, float4 x,
                                      float4& a0, float4& a1, float4& a2, float4& a3) {
    a0.x = fmaf(w.x, x.x, a0.x); a0.y = fmaf(w.y, x.x, a0.y);
    a0.z = fmaf(w.z, x.x, a0.z); a0.w = fmaf(w.w, x.x, a0.w);
    a1.x = fmaf(w.x, x.y, a1.x); a1.y = fmaf(w.y, x.y, a1.y);
    a1.z = fmaf(w.z, x.y, a1.z); a1.w = fmaf(w.w, x.y, a1.w);
    a2.x = fmaf(w.x, x.z, a2.x); a2.y = fmaf(w.y, x.z, a2.y);
    a2.z = fmaf(w.z, x.z, a2.z); a2.w = fmaf(w.w, x.z, a2.w);
    a3.x = fmaf(w.x, x.w, a3.x); a3.y = fmaf(w.y, x.w, a3.y);
    a3.z = fmaf(w.z, x.w, a3.z); a3.w = fmaf(w.w, x.w, a3.w);
}

// ---------------- main kernel ----------------

struct Args {
    const float *params, *disp;
    const float *embed_b, *embed_g, *embed_beta;
    const float *skip_b;
    const float *gates_b;
    const float *inln_g, *inln_b, *hln_g, *hln_b, *sln_g, *sln_b;
    const float *ab1, *aw2, *ab2;
    const float *rb1, *rb2, *rln_g, *rln_b;
    const float *ob1, *oln_g, *oln_b, *ow2, *ob2;
    const float *gw, *a1w, *r1w, *r2w, *ew, *sw, *o1w;
    float* out;
    float* act;   // cluster activation buffers
    int* bar;     // per-member flags, 16-int stride, 128 ints per cluster
};

__global__ __launch_bounds__(NTH) void xlstm_kernel(Args A) {
    const int tid = threadIdx.x;
    const int cid = blockIdx.x & 31;   // cluster id; members share XCD (blockIdx%8)
    const int m   = blockIdx.x >> 5;   // member 0..7
    const int n   = tid & 255;
    const int p   = tid >> 8;          // 0/1 -> rows p, p+2
    const int rA = p, rB = p + 2;

    float* gatesB = A.act + (size_t)cid * ACTSTRIDE;   // [4][1024]
    float* a1B  = gatesB + 4096;                       // [8][4] imp partials
    float* r2P  = gatesB + 4224;                       // [8][4][256] r2 partials
    float* o1B  = gatesB + 12416;                      // [2][4][128] (parity slots)
    int* myflag = A.bar + cid * 128 + m * 16;

    // LDS. P4 planes: [row][kg][j], plane stride padded (516/260) in float4s.
    __shared__ __align__(16) float4 P4[2064];     // 33 KB partials
    __shared__ __align__(16) float4 xnhnT[512];
    __shared__ __align__(16) float4 cT4[256];
    __shared__ __align__(16) float4 hT4[256];
    __shared__ __align__(16) float4 xT4[256];
    __shared__ __align__(16) float4 skT4[128];
    __shared__ __align__(16) float4 r1locT[64];   // member's r1 slice, [local_k][row]
    __shared__ float xtT[17 * 4];
    __shared__ float scr[64];

    float x2[2] = {0.f, 0.f};
    float h2[LL][2] = {{0.f,0.f},{0.f,0.f},{0.f,0.f}};
    float c2[LL][2] = {{0.f,0.f},{0.f,0.f},{0.f,0.f}};

    int ep = 0;
    // Relaxed-poll cluster barrier: exactly ONE release fence per signal and
    // ONE acquire fence per wait (vs per-poll-iteration cache ops, which
    // hammer the XCD L2 with buffer_inv/wbl2 and serialize everything).
    auto csig = [&]() {
        ep++;
        __syncthreads();   // every wave drains its stores (s_barrier implies vmcnt(0))
        if (tid == 0) {
            __builtin_amdgcn_fence(__ATOMIC_RELEASE, "agent");   // one wbl2
            __hip_atomic_store(myflag, ep, __ATOMIC_RELAXED, __HIP_MEMORY_SCOPE_AGENT);
        }
    };
    auto cwait = [&]() {
        if (tid == 0) {
#pragma unroll 1
            for (int mm = 0; mm < SWG; mm++) {
                const int* f = A.bar + cid * 128 + mm * 16;
                while (__hip_atomic_load(f, __ATOMIC_RELAXED, __HIP_MEMORY_SCOPE_AGENT) < ep)
                    __builtin_amdgcn_s_sleep(4);
            }
            __builtin_amdgcn_fence(__ATOMIC_ACQUIRE, "agent");   // one inv
        }
        __syncthreads();
    };

    if (tid < 64) {
        int k = tid >> 2, rr = tid & 3;
        xtT[(1 + k) * 4 + rr] = A.params[(RW * cid + rr) * 16 + k];
    }
    __syncthreads();

    for (int t = 0; t < TT; t++) {
        if (tid < 4) xtT[tid] = A.disp[(RW * cid + tid) * TT + t];
        __syncthreads();

        // ---- embed + skip (redundant in every member) ----
        float e0 = A.embed_b[n], e1 = e0;
#pragma unroll 4
        for (int k = 0; k < 17; k++) {
            float w = A.ew[k * 256 + n];
            e0 = fmaf(w, xtT[k * 4 + rA], e0);
            e1 = fmaf(w, xtT[k * 4 + rB], e1);
        }
        {
            int mm = tid & 127, q = tid >> 7;
            float s = A.skip_b[mm];
#pragma unroll 4
            for (int k = 0; k < 17; k++) s = fmaf(A.sw[k * 128 + mm], xtT[k * 4 + q], s);
            ((float*)&skT4[mm])[q] = relu(s);
        }
        float4 rs = rowsum4(e0, e0 * e0, e1, e1 * e1, scr, tid);
        {
            float mu = rs.x * (1.f/HH), inv = rsqrtf(rs.y * (1.f/HH) - mu*mu + LN_EPS);
            x2[0] = relu((e0 - mu) * inv * A.embed_g[n] + A.embed_beta[n]);
            mu = rs.z * (1.f/HH); inv = rsqrtf(rs.w * (1.f/HH) - mu*mu + LN_EPS);
            x2[1] = relu((e1 - mu) * inv * A.embed_g[n] + A.embed_beta[n]);
        }

#pragma unroll 1
        for (int l = 0; l < LL; l++) {
            // ---- phase A (redundant): xn, hn, stage cT ----
            rs = rowsum4(x2[0], x2[0]*x2[0], x2[1], x2[1]*x2[1], scr, tid);
            {
                const float* g = A.inln_g + l*HH; const float* b = A.inln_b + l*HH;
                float mu = rs.x*(1.f/HH), inv = rsqrtf(rs.y*(1.f/HH) - mu*mu + LN_EPS);
                ((float*)&xnhnT[n])[rA] = (x2[0] - mu) * inv * g[n] + b[n];
                mu = rs.z*(1.f/HH); inv = rsqrtf(rs.w*(1.f/HH) - mu*mu + LN_EPS);
                ((float*)&xnhnT[n])[rB] = (x2[1] - mu) * inv * g[n] + b[n];
            }
            float hA = h2[l][0], hB = h2[l][1];
            rs = rowsum4(hA, hA*hA, hB, hB*hB, scr, tid);
            {
                const float* g = A.hln_g + l*HH; const float* b = A.hln_b + l*HH;
                float mu = rs.x*(1.f/HH), inv = rsqrtf(rs.y*(1.f/HH) - mu*mu + LN_EPS);
                ((float*)&xnhnT[256 + n])[rA] = (hA - mu) * inv * g[n] + b[n];
                mu = rs.z*(1.f/HH); inv = rsqrtf(rs.w*(1.f/HH) - mu*mu + LN_EPS);
                ((float*)&xnhnT[256 + n])[rB] = (hB - mu) * inv * g[n] + b[n];
            }
            ((float*)&cT4[n])[rA] = c2[l][0];
            ((float*)&cT4[n])[rB] = c2[l][1];
            __syncthreads();

            // ---- MV1: gates N-slice (K=512, 32 f4-cols). KG=16, PL=516 ----
            {
                int j = tid & 31, kg = tid >> 5;
                const float4* Wq = (const float4*)A.gw + (size_t)l*512*256 + (m*32 + j);
                float4 a0={0,0,0,0}, a1v={0,0,0,0}, a2={0,0,0,0}, a3={0,0,0,0};
                int k0 = kg * 32;
#pragma unroll 8
                for (int kk = 0; kk < 32; kk++) {
                    int k = k0 + kk;
                    fma16(Wq[(size_t)k * 256], xnhnT[k], a0, a1v, a2, a3);
                }
                int b = kg*32 + j;
                P4[b] = a0; P4[516 + b] = a1v; P4[2*516 + b] = a2; P4[3*516 + b] = a3;
            }
            __syncthreads();
            if (tid < 128) {
                int j2 = tid >> 2, row = tid & 3;
                float4 s = {0,0,0,0};
#pragma unroll
                for (int kg = 0; kg < 16; kg++) {
                    float4 v = P4[row*516 + kg*32 + j2];
                    s.x += v.x; s.y += v.y; s.z += v.z; s.w += v.w;
                }
                ((float4*)(gatesB + row*1024 + m*128))[j2] = s;
            }
            __syncthreads();
            // ---- MV1b: a1 N-slice (K=256, 8 f4-cols). KG=32, PL=260 ----
            if (tid < 256) {
                int j = tid & 7, kg = tid >> 3;
                const float4* Wq = (const float4*)A.a1w + (size_t)l*256*64 + (m*8 + j);
                float4 a0={0,0,0,0}, a1v={0,0,0,0}, a2={0,0,0,0}, a3={0,0,0,0};
                int k0 = kg * 8;
#pragma unroll
                for (int kk = 0; kk < 8; kk++) {
                    int k = k0 + kk;
                    fma16(Wq[(size_t)k * 64], cT4[k], a0, a1v, a2, a3);
                }
                int b = kg*8 + j;
                P4[b] = a0; P4[260 + b] = a1v; P4[2*260 + b] = a2; P4[3*260 + b] = a3;
            }
            __syncthreads();
            if (tid < 32) {
                int j2 = tid >> 2, row = tid & 3;
                float4 s = {0,0,0,0};
#pragma unroll
                for (int kg = 0; kg < 32; kg++) {
                    float4 v = P4[row*260 + kg*8 + j2];
                    s.x += v.x; s.y += v.y; s.z += v.z; s.w += v.w;
                }
                const float* ab1p = A.ab1 + l*HH + m*32 + j2*4;
                const float* aw2p = A.aw2 + l*HH + m*32 + j2*4;
                float d = fast_tanh(s.x + ab1p[0]) * aw2p[0]
                        + fast_tanh(s.y + ab1p[1]) * aw2p[1]
                        + fast_tanh(s.z + ab1p[2]) * aw2p[2]
                        + fast_tanh(s.w + ab1p[3]) * aw2p[3];
                scr[tid] = d;
            }
            __syncthreads();
            if (tid < 4) {
                float s = 0.f;
#pragma unroll
                for (int j2 = 0; j2 < 8; j2++) s += scr[j2*4 + tid];
                a1B[m*4 + tid] = s;
            }
            csig(); cwait();   // B1: gates + a1 partials visible

            // ---- phase B (redundant): imp, c, h ----
            float imp0, imp1;
            {
                float sA = A.ab2[l], sB = A.ab2[l];
#pragma unroll
                for (int mm = 0; mm < SWG; mm++) { sA += a1B[mm*4 + rA]; sB += a1B[mm*4 + rB]; }
                imp0 = fast_sigmoid(sA); imp1 = fast_sigmoid(sB);
            }
            const float* gb = A.gates_b + l*1024;
            float craw0, craw1, og0, og1;
            {
                const float* go = gatesB + rA*1024;
                float ii = fast_sigmoid(go[n] + gb[n]);
                float ff = fast_sigmoid(go[256+n] + gb[256+n]);
                float gg = fast_tanh(go[512+n] + gb[512+n]);
                og0 = fast_sigmoid(go[768+n] + gb[768+n]);
                craw0 = (ff * c2[l][0] + ii * gg) * imp0;
            }
            {
                const float* go = gatesB + rB*1024;
                float ii = fast_sigmoid(go[n] + gb[n]);
                float ff = fast_sigmoid(go[256+n] + gb[256+n]);
                float gg = fast_tanh(go[512+n] + gb[512+n]);
                og1 = fast_sigmoid(go[768+n] + gb[768+n]);
                craw1 = (ff * c2[l][1] + ii * gg) * imp1;
            }
            rs = rowsum4(craw0, craw0*craw0, craw1, craw1*craw1, scr, tid);
            {
                const float* g = A.sln_g + l*HH; const float* b = A.sln_b + l*HH;
                float mu = rs.x*(1.f/HH), inv = rsqrtf(rs.y*(1.f/HH) - mu*mu + LN_EPS);
                float cn = (craw0 - mu) * inv * g[n] + b[n];
                c2[l][0] = cn; float hh = og0 * fast_tanh(cn);
                h2[l][0] = hh; ((float*)&hT4[n])[rA] = hh;
                mu = rs.z*(1.f/HH); inv = rsqrtf(rs.w*(1.f/HH) - mu*mu + LN_EPS);
                cn = (craw1 - mu) * inv * g[n] + b[n];
                c2[l][1] = cn; hh = og1 * fast_tanh(cn);
                h2[l][1] = hh; ((float*)&hT4[n])[rB] = hh;
            }
            __syncthreads();

            // ---- MV2: r1 N-slice (K=256, 16 f4-cols). KG=32, PL=516 ----
            {
                int j = tid & 15, kg = tid >> 4;
                const float4* Wq = (const float4*)A.r1w + (size_t)l*256*128 + (m*16 + j);
                float4 a0={0,0,0,0}, a1v={0,0,0,0}, a2={0,0,0,0}, a3={0,0,0,0};
                int k0 = kg * 8;
#pragma unroll
                for (int kk = 0; kk < 8; kk++) {
                    int k = k0 + kk;
                    fma16(Wq[(size_t)k * 128], hT4[k], a0, a1v, a2, a3);
                }
                int b = kg*16 + j;
                P4[b] = a0; P4[516 + b] = a1v; P4[2*516 + b] = a2; P4[3*516 + b] = a3;
            }
            __syncthreads();
            if (tid < 64) {
                int j2 = tid >> 2, row = tid & 3;
                float4 s = {0,0,0,0};
#pragma unroll
                for (int kg = 0; kg < 32; kg++) {
                    float4 v = P4[row*516 + kg*16 + j2];
                    s.x += v.x; s.y += v.y; s.z += v.z; s.w += v.w;
                }
                const float* rb1p = A.rb1 + l*512 + m*64 + j2*4;
                ((float*)&r1locT[j2*4 + 0])[row] = relu(s.x + rb1p[0]);
                ((float*)&r1locT[j2*4 + 1])[row] = relu(s.y + rb1p[1]);
                ((float*)&r1locT[j2*4 + 2])[row] = relu(s.z + rb1p[2]);
                ((float*)&r1locT[j2*4 + 3])[row] = relu(s.w + rb1p[3]);
            }
            __syncthreads();

            // ---- MV3: r2 K-slice (rows m*64..m*64+63, all 64 f4-cols).
            //      Uses ONLY local r1 slice -> no barrier before it.
            {
                int j = tid & 63, kg = tid >> 6;
                const float4* Wq = (const float4*)A.r2w + (size_t)l*512*64
                                   + (size_t)(m*64) * 64 + j;
                float4 a0={0,0,0,0}, a1v={0,0,0,0}, a2={0,0,0,0}, a3={0,0,0,0};
                int k0 = kg * 8;
#pragma unroll
                for (int kk = 0; kk < 8; kk++) {
                    int lk = k0 + kk;
                    fma16(Wq[(size_t)lk * 64], r1locT[lk], a0, a1v, a2, a3);
                }
                int b = kg*64 + j;
                P4[b] = a0; P4[516 + b] = a1v; P4[2*516 + b] = a2; P4[3*516 + b] = a3;
            }
            __syncthreads();
            {
                int j2 = tid >> 2, row = tid & 3;
                if (tid < 256) {
                    float4 s = {0,0,0,0};
#pragma unroll
                    for (int kg = 0; kg < 8; kg++) {
                        float4 v = P4[row*516 + kg*64 + j2];
                        s.x += v.x; s.y += v.y; s.z += v.z; s.w += v.w;
                    }
                    ((float4*)(r2P + m*1024 + row*256))[j2] = s;
                }
            }
            csig(); cwait();   // B2: r2 partials visible

            // ---- phase C (redundant): x = LN(sum r2 partials + rb2 + h) + res ----
            const float* rb2p = A.rb2 + l*HH;
            float s0 = rb2p[n] + h2[l][0];
            float s1 = rb2p[n] + h2[l][1];
#pragma unroll
            for (int mm = 0; mm < SWG; mm++) {
                s0 += r2P[mm*1024 + rA*256 + n];
                s1 += r2P[mm*1024 + rB*256 + n];
            }
            rs = rowsum4(s0, s0*s0, s1, s1*s1, scr, tid);
            {
                const float* g = A.rln_g + l*HH; const float* b = A.rln_b + l*HH;
                float mu = rs.x*(1.f/HH), inv = rsqrtf(rs.y*(1.f/HH) - mu*mu + LN_EPS);
                x2[0] = (s0 - mu) * inv * g[n] + b[n] + x2[0];
                mu = rs.z*(1.f/HH); inv = rsqrtf(rs.w*(1.f/HH) - mu*mu + LN_EPS);
                x2[1] = (s1 - mu) * inv * g[n] + b[n] + x2[1];
            }
        }   // layers

        // ---- head: o1 N-slice (K=384, 4 f4-cols). KG=128, PL=516 ----
        ((float*)&xT4[n])[rA] = x2[0];
        ((float*)&xT4[n])[rB] = x2[1];
        __syncthreads();
        {
            int j = tid & 3, kg = tid >> 2;
            const float4* Wq = (const float4*)A.o1w + (m*4 + j);
            float4 a0={0,0,0,0}, a1v={0,0,0,0}, a2={0,0,0,0}, a3={0,0,0,0};
            int k0 = kg * 3;
#pragma unroll
            for (int kk = 0; kk < 3; kk++) {
                int k = k0 + kk;
                float4 x = (k < 256) ? xT4[k] : skT4[k - 256];
                fma16(Wq[(size_t)k * 32], x, a0, a1v, a2, a3);
            }
            int b = kg*4 + j;
            P4[b] = a0; P4[516 + b] = a1v; P4[2*516 + b] = a2; P4[3*516 + b] = a3;
        }
        __syncthreads();
        float* o1S = o1B + (t & 1) * 512;
        if (tid < 16) {
            int j2 = tid >> 2, row = tid & 3;
            float4 s = {0,0,0,0};
#pragma unroll
            for (int kg = 0; kg < 128; kg++) {
                float4 v = P4[row*516 + kg*4 + j2];
                s.x += v.x; s.y += v.y; s.z += v.z; s.w += v.w;
            }
            ((float4*)(o1S + row*128 + m*16))[j2] = s;
        }
        csig();            // head partials signaled by all members
        if (m == 0) {
            cwait();       // only m0 consumes o1
            int mm = tid & 127, row = tid >> 7;
            float v = o1S[row*128 + mm] + A.ob1[mm];
            float2 f2 = red2head(v, v * v, scr, tid);
            float mu = f2.x * (1.f/128.f);
            float inv = rsqrtf(f2.y * (1.f/128.f) - mu*mu + LN_EPS);
            float contrib = relu((v - mu) * inv * A.oln_g[mm] + A.oln_b[mm]) * A.ow2[mm];
            f2 = red2head(contrib, 0.f, scr, tid);
            if (mm == 0) A.out[(RW*cid + row) * TT + t] = f2.x + A.ob2[0];
        }
        __syncthreads();   // protect LDS for next step
    }
}

// ---------------- launch ----------------

extern "C" void kernel_launch(void* const* d_in, const int* in_sizes, int n_in,
                              void* d_out, int out_size, void* d_ws, size_t ws_size,
                              hipStream_t stream) {
    // zero per-member flag region (32 clusters x 128 ints)
    hipMemsetAsync(d_ws, 0, CLN * 128 * sizeof(int), stream);

    Args A;
    A.params     = (const float*)d_in[0];
    A.disp       = (const float*)d_in[1];
    A.ew         = (const float*)d_in[2];
    A.embed_b    = (const float*)d_in[3];
    A.embed_g    = (const float*)d_in[4];
    A.embed_beta = (const float*)d_in[5];
    A.sw         = (const float*)d_in[6];
    A.skip_b     = (const float*)d_in[7];
    A.gw         = (const float*)d_in[8];
    A.gates_b    = (const float*)d_in[9];
    A.inln_g     = (const float*)d_in[10];
    A.inln_b     = (const float*)d_in[11];
    A.hln_g      = (const float*)d_in[12];
    A.hln_b      = (const float*)d_in[13];
    A.sln_g      = (const float*)d_in[14];
    A.sln_b      = (const float*)d_in[15];
    A.a1w        = (const float*)d_in[16];
    A.ab1        = (const float*)d_in[17];
    A.aw2        = (const float*)d_in[18];
    A.ab2        = (const float*)d_in[19];
    A.r1w        = (const float*)d_in[20];
    A.rb1        = (const float*)d_in[21];
    A.r2w        = (const float*)d_in[22];
    A.rb2        = (const float*)d_in[23];
    A.rln_g      = (const float*)d_in[24];
    A.rln_b      = (const float*)d_in[25];
    A.o1w        = (const float*)d_in[26];
    A.ob1        = (const float*)d_in[27];
    A.oln_g      = (const float*)d_in[28];
    A.oln_b      = (const float*)d_in[29];
    A.ow2        = (const float*)d_in[30];
    A.ob2        = (const float*)d_in[31];
    A.out        = (float*)d_out;
    A.bar        = (int*)d_ws;
    A.act        = (float*)d_ws + CLN * 128;

    xlstm_kernel<<<CLN * SWG, NTH, 0, stream>>>(A);
}

// Round 11
// 26383.420 us; speedup vs baseline: 1.3442x; 1.2050x over previous
//
#include <hip/hip_runtime.h>
#include <cstdint>

#define TT 256
#define HH 256
#define LL 3
#define NTH 512
#define SWG 8          // WGs per cluster
#define CLN 32         // clusters
#define RW 4           // rows per cluster
#define LN_EPS 1e-5f
#define ACTSTRIDE 16384 // floats per cluster in d_ws act region

// ---------------- helpers ----------------

__device__ __forceinline__ float fast_sigmoid(float x) {
    return 1.f / (1.f + __expf(-x));
}
__device__ __forceinline__ float fast_tanh(float x) {
    float xc = fminf(fmaxf(x, -15.f), 15.f);
    float e = __expf(2.f * xc);
    return 1.f - 2.f / (e + 1.f);
}
__device__ __forceinline__ float relu(float x) { return fmaxf(x, 0.f); }

// LLC-coherent scalar access (lowered to global_load/store sc0 sc1: bypasses
// the non-coherent L1/L2, pipelined under vmcnt, NO cache-maintenance ops).
__device__ __forceinline__ void cst(float* p, float v) {
    __hip_atomic_store(p, v, __ATOMIC_RELAXED, __HIP_MEMORY_SCOPE_AGENT);
}
__device__ __forceinline__ float cld(const float* p) {
    return __hip_atomic_load(p, __ATOMIC_RELAXED, __HIP_MEMORY_SCOPE_AGENT);
}

// Dual-row (sum, sumsq) reduction. Thread (n=tid&255, p=tid>>8) owns rows
// p and p+2. Returns (sumA, sqA, sumB, sqB). scr: 32 floats.
__device__ __forceinline__ float4 rowsum4(float s0, float q0, float s1, float q1,
                                          float* scr, int tid) {
#pragma unroll
    for (int o = 32; o > 0; o >>= 1) {
        s0 += __shfl_down(s0, o); q0 += __shfl_down(q0, o);
        s1 += __shfl_down(s1, o); q1 += __shfl_down(q1, o);
    }
    int w = tid >> 6;
    if ((tid & 63) == 0) { scr[w*4] = s0; scr[w*4+1] = q0; scr[w*4+2] = s1; scr[w*4+3] = q1; }
    __syncthreads();
    int base = (tid >> 8) * 16;
    float sA = 0, qA = 0, sB = 0, qB = 0;
#pragma unroll
    for (int i = 0; i < 4; i++) {
        sA += scr[base + i*4];     qA += scr[base + i*4 + 1];
        sB += scr[base + i*4 + 2]; qB += scr[base + i*4 + 3];
    }
    __syncthreads();
    return make_float4(sA, qA, sB, qB);
}

// Head reduction: thread (mm=tid&127, row=tid>>7); row r spans waves 2r,2r+1.
__device__ __forceinline__ float2 red2head(float a, float b, float* scr, int tid) {
#pragma unroll
    for (int o = 32; o > 0; o >>= 1) {
        a += __shfl_down(a, o);
        b += __shfl_down(b, o);
    }
    int w = tid >> 6;
    if ((tid & 63) == 0) { scr[w] = a; scr[8 + w] = b; }
    __syncthreads();
    int r = tid >> 7;
    float2 out = make_float2(scr[2*r] + scr[2*r+1], scr[8+2*r] + scr[8+2*r+1]);
    __syncthreads();
    return out;
}

__device__ __forceinline__ void fma16(float4 w, float4 x,
                                      float4& a0, float4& a1, float4& a2, float4& a3) {
    a0.x = fmaf(w.x, x.x, a0.x); a0.y = fmaf(w.y, x.x, a0.y);
    a0.z = fmaf(w.z, x.x, a0.z); a0.w = fmaf(w.w, x.x, a0.w);
    a1.x = fmaf(w.x, x.y, a1.x); a1.y = fmaf(w.y, x.y, a1.y);
    a1.z = fmaf(w.z, x.y, a1.z); a1.w = fmaf(w.w, x.y, a1.w);
    a2.x = fmaf(w.x, x.z, a2.x); a2.y = fmaf(w.y, x.z, a2.y);
    a2.z = fmaf(w.z, x.z, a2.z); a2.w = fmaf(w.w, x.z, a2.w);
    a3.x = fmaf(w.x, x.w, a3.x); a3.y = fmaf(w.y, x.w, a3.y);
    a3.z = fmaf(w.z, x.w, a3.z); a3.w = fmaf(w.w, x.w, a3.w);
}

// ---------------- main kernel ----------------

struct Args {
    const float *params, *disp;
    const float *embed_b, *embed_g, *embed_beta;
    const float *skip_b;
    const float *gates_b;
    const float *inln_g, *inln_b, *hln_g, *hln_b, *sln_g, *sln_b;
    const float *ab1, *aw2, *ab2;
    const float *rb1, *rb2, *rln_g, *rln_b;
    const float *ob1, *oln_g, *oln_b, *ow2, *ob2;
    const float *gw, *a1w, *r1w, *r2w, *ew, *sw, *o1w;
    float* out;
    float* act;   // cluster activation buffers (accessed ONLY via cst/cld)
    int* bar;     // per-member flags, 16-int stride, 128 ints per cluster
};

__global__ __launch_bounds__(NTH) void xlstm_kernel(Args A) {
    const int tid = threadIdx.x;
    const int cid = blockIdx.x & 31;   // cluster id; members share XCD (blockIdx%8)
    const int m   = blockIdx.x >> 5;   // member 0..7
    const int n   = tid & 255;
    const int p   = tid >> 8;          // 0/1 -> rows p, p+2
    const int rA = p, rB = p + 2;

    float* gatesB = A.act + (size_t)cid * ACTSTRIDE;   // [4][1024]
    float* a1B  = gatesB + 4096;                       // [8][4] imp partials
    float* r2P  = gatesB + 4224;                       // [8][4][256] r2 partials
    float* o1B  = gatesB + 12416;                      // [2][4][128] (parity slots)
    int* myflag = A.bar + cid * 128 + m * 16;

    // LDS. P4 planes: [row][kg][j], plane stride padded (516/260) in float4s.
    __shared__ __align__(16) float4 P4[2064];     // 33 KB partials
    __shared__ __align__(16) float4 xnhnT[512];
    __shared__ __align__(16) float4 cT4[256];
    __shared__ __align__(16) float4 hT4[256];
    __shared__ __align__(16) float4 xT4[256];
    __shared__ __align__(16) float4 skT4[128];
    __shared__ __align__(16) float4 r1locT[64];   // member's r1 slice, [local_k][row]
    __shared__ float xtT[17 * 4];
    __shared__ float scr[64];

    float x2[2] = {0.f, 0.f};
    float h2[LL][2] = {{0.f,0.f},{0.f,0.f},{0.f,0.f}};
    float c2[LL][2] = {{0.f,0.f},{0.f,0.f},{0.f,0.f}};

    int ep = 0;
    // Fence-free cluster barrier: all cross-WG data moves via LLC-coherent
    // cst/cld, so NO buffer_wbl2/buffer_inv is ever needed. __syncthreads
    // drains vmcnt before the flag store (compiler emits vmcnt(0) before
    // s_barrier); a compiler-only barrier orders post-wait loads.
    auto csig = [&]() {
        ep++;
        __syncthreads();   // all WG cst stores drained to LLC
        if (tid == 0)
            __hip_atomic_store(myflag, ep, __ATOMIC_RELAXED, __HIP_MEMORY_SCOPE_AGENT);
    };
    auto cwait = [&]() {
        if (tid == 0) {
#pragma unroll 1
            for (int mm = 0; mm < SWG; mm++) {
                const int* f = A.bar + cid * 128 + mm * 16;
                while (__hip_atomic_load(f, __ATOMIC_RELAXED, __HIP_MEMORY_SCOPE_AGENT) < ep)
                    __builtin_amdgcn_s_sleep(4);
            }
            asm volatile("" ::: "memory");   // compiler ordering only
        }
        __syncthreads();
    };

    if (tid < 64) {
        int k = tid >> 2, rr = tid & 3;
        xtT[(1 + k) * 4 + rr] = A.params[(RW * cid + rr) * 16 + k];
    }
    __syncthreads();

    for (int t = 0; t < TT; t++) {
        if (tid < 4) xtT[tid] = A.disp[(RW * cid + tid) * TT + t];
        __syncthreads();

        // ---- embed + skip (redundant in every member) ----
        float e0 = A.embed_b[n], e1 = e0;
#pragma unroll 4
        for (int k = 0; k < 17; k++) {
            float w = A.ew[k * 256 + n];
            e0 = fmaf(w, xtT[k * 4 + rA], e0);
            e1 = fmaf(w, xtT[k * 4 + rB], e1);
        }
        {
            int mm = tid & 127, q = tid >> 7;
            float s = A.skip_b[mm];
#pragma unroll 4
            for (int k = 0; k < 17; k++) s = fmaf(A.sw[k * 128 + mm], xtT[k * 4 + q], s);
            ((float*)&skT4[mm])[q] = relu(s);
        }
        float4 rs = rowsum4(e0, e0 * e0, e1, e1 * e1, scr, tid);
        {
            float mu = rs.x * (1.f/HH), inv = rsqrtf(rs.y * (1.f/HH) - mu*mu + LN_EPS);
            x2[0] = relu((e0 - mu) * inv * A.embed_g[n] + A.embed_beta[n]);
            mu = rs.z * (1.f/HH); inv = rsqrtf(rs.w * (1.f/HH) - mu*mu + LN_EPS);
            x2[1] = relu((e1 - mu) * inv * A.embed_g[n] + A.embed_beta[n]);
        }

#pragma unroll 1
        for (int l = 0; l < LL; l++) {
            // ---- phase A (redundant): xn, hn, stage cT ----
            rs = rowsum4(x2[0], x2[0]*x2[0], x2[1], x2[1]*x2[1], scr, tid);
            {
                const float* g = A.inln_g + l*HH; const float* b = A.inln_b + l*HH;
                float mu = rs.x*(1.f/HH), inv = rsqrtf(rs.y*(1.f/HH) - mu*mu + LN_EPS);
                ((float*)&xnhnT[n])[rA] = (x2[0] - mu) * inv * g[n] + b[n];
                mu = rs.z*(1.f/HH); inv = rsqrtf(rs.w*(1.f/HH) - mu*mu + LN_EPS);
                ((float*)&xnhnT[n])[rB] = (x2[1] - mu) * inv * g[n] + b[n];
            }
            float hA = h2[l][0], hB = h2[l][1];
            rs = rowsum4(hA, hA*hA, hB, hB*hB, scr, tid);
            {
                const float* g = A.hln_g + l*HH; const float* b = A.hln_b + l*HH;
                float mu = rs.x*(1.f/HH), inv = rsqrtf(rs.y*(1.f/HH) - mu*mu + LN_EPS);
                ((float*)&xnhnT[256 + n])[rA] = (hA - mu) * inv * g[n] + b[n];
                mu = rs.z*(1.f/HH); inv = rsqrtf(rs.w*(1.f/HH) - mu*mu + LN_EPS);
                ((float*)&xnhnT[256 + n])[rB] = (hB - mu) * inv * g[n] + b[n];
            }
            ((float*)&cT4[n])[rA] = c2[l][0];
            ((float*)&cT4[n])[rB] = c2[l][1];
            __syncthreads();

            // ---- MV1: gates N-slice (K=512, 32 f4-cols). KG=16, PL=516 ----
            {
                int j = tid & 31, kg = tid >> 5;
                const float4* Wq = (const float4*)A.gw + (size_t)l*512*256 + (m*32 + j);
                float4 a0={0,0,0,0}, a1v={0,0,0,0}, a2={0,0,0,0}, a3={0,0,0,0};
                int k0 = kg * 32;
#pragma unroll 8
                for (int kk = 0; kk < 32; kk++) {
                    int k = k0 + kk;
                    fma16(Wq[(size_t)k * 256], xnhnT[k], a0, a1v, a2, a3);
                }
                int b = kg*32 + j;
                P4[b] = a0; P4[516 + b] = a1v; P4[2*516 + b] = a2; P4[3*516 + b] = a3;
            }
            __syncthreads();
            if (tid < 128) {
                int j2 = tid >> 2, row = tid & 3;
                float4 s = {0,0,0,0};
#pragma unroll
                for (int kg = 0; kg < 16; kg++) {
                    float4 v = P4[row*516 + kg*32 + j2];
                    s.x += v.x; s.y += v.y; s.z += v.z; s.w += v.w;
                }
                float* d = gatesB + row*1024 + m*128 + j2*4;
                cst(d+0, s.x); cst(d+1, s.y); cst(d+2, s.z); cst(d+3, s.w);
            }
            __syncthreads();
            // ---- MV1b: a1 N-slice (K=256, 8 f4-cols). KG=32, PL=260 ----
            if (tid < 256) {
                int j = tid & 7, kg = tid >> 3;
                const float4* Wq = (const float4*)A.a1w + (size_t)l*256*64 + (m*8 + j);
                float4 a0={0,0,0,0}, a1v={0,0,0,0}, a2={0,0,0,0}, a3={0,0,0,0};
                int k0 = kg * 8;
#pragma unroll
                for (int kk = 0; kk < 8; kk++) {
                    int k = k0 + kk;
                    fma16(Wq[(size_t)k * 64], cT4[k], a0, a1v, a2, a3);
                }
                int b = kg*8 + j;
                P4[b] = a0; P4[260 + b] = a1v; P4[2*260 + b] = a2; P4[3*260 + b] = a3;
            }
            __syncthreads();
            if (tid < 32) {
                int j2 = tid >> 2, row = tid & 3;
                float4 s = {0,0,0,0};
#pragma unroll
                for (int kg = 0; kg < 32; kg++) {
                    float4 v = P4[row*260 + kg*8 + j2];
                    s.x += v.x; s.y += v.y; s.z += v.z; s.w += v.w;
                }
                const float* ab1p = A.ab1 + l*HH + m*32 + j2*4;
                const float* aw2p = A.aw2 + l*HH + m*32 + j2*4;
                float d = fast_tanh(s.x + ab1p[0]) * aw2p[0]
                        + fast_tanh(s.y + ab1p[1]) * aw2p[1]
                        + fast_tanh(s.z + ab1p[2]) * aw2p[2]
                        + fast_tanh(s.w + ab1p[3]) * aw2p[3];
                scr[tid] = d;
            }
            __syncthreads();
            if (tid < 4) {
                float s = 0.f;
#pragma unroll
                for (int j2 = 0; j2 < 8; j2++) s += scr[j2*4 + tid];
                cst(a1B + m*4 + tid, s);
            }
            csig(); cwait();   // B1: gates + a1 partials visible

            // ---- phase B (redundant): imp, c, h ----
            float imp0, imp1;
            {
                float sA = A.ab2[l], sB = A.ab2[l];
#pragma unroll
                for (int mm = 0; mm < SWG; mm++) {
                    sA += cld(a1B + mm*4 + rA);
                    sB += cld(a1B + mm*4 + rB);
                }
                imp0 = fast_sigmoid(sA); imp1 = fast_sigmoid(sB);
            }
            const float* gb = A.gates_b + l*1024;
            float craw0, craw1, og0, og1;
            {
                const float* go = gatesB + rA*1024;
                float ii = fast_sigmoid(cld(go + n) + gb[n]);
                float ff = fast_sigmoid(cld(go + 256 + n) + gb[256+n]);
                float gg = fast_tanh(cld(go + 512 + n) + gb[512+n]);
                og0 = fast_sigmoid(cld(go + 768 + n) + gb[768+n]);
                craw0 = (ff * c2[l][0] + ii * gg) * imp0;
            }
            {
                const float* go = gatesB + rB*1024;
                float ii = fast_sigmoid(cld(go + n) + gb[n]);
                float ff = fast_sigmoid(cld(go + 256 + n) + gb[256+n]);
                float gg = fast_tanh(cld(go + 512 + n) + gb[512+n]);
                og1 = fast_sigmoid(cld(go + 768 + n) + gb[768+n]);
                craw1 = (ff * c2[l][1] + ii * gg) * imp1;
            }
            rs = rowsum4(craw0, craw0*craw0, craw1, craw1*craw1, scr, tid);
            {
                const float* g = A.sln_g + l*HH; const float* b = A.sln_b + l*HH;
                float mu = rs.x*(1.f/HH), inv = rsqrtf(rs.y*(1.f/HH) - mu*mu + LN_EPS);
                float cn = (craw0 - mu) * inv * g[n] + b[n];
                c2[l][0] = cn; float hh = og0 * fast_tanh(cn);
                h2[l][0] = hh; ((float*)&hT4[n])[rA] = hh;
                mu = rs.z*(1.f/HH); inv = rsqrtf(rs.w*(1.f/HH) - mu*mu + LN_EPS);
                cn = (craw1 - mu) * inv * g[n] + b[n];
                c2[l][1] = cn; hh = og1 * fast_tanh(cn);
                h2[l][1] = hh; ((float*)&hT4[n])[rB] = hh;
            }
            __syncthreads();

            // ---- MV2: r1 N-slice (K=256, 16 f4-cols). KG=32, PL=516 ----
            {
                int j = tid & 15, kg = tid >> 4;
                const float4* Wq = (const float4*)A.r1w + (size_t)l*256*128 + (m*16 + j);
                float4 a0={0,0,0,0}, a1v={0,0,0,0}, a2={0,0,0,0}, a3={0,0,0,0};
                int k0 = kg * 8;
#pragma unroll
                for (int kk = 0; kk < 8; kk++) {
                    int k = k0 + kk;
                    fma16(Wq[(size_t)k * 128], hT4[k], a0, a1v, a2, a3);
                }
                int b = kg*16 + j;
                P4[b] = a0; P4[516 + b] = a1v; P4[2*516 + b] = a2; P4[3*516 + b] = a3;
            }
            __syncthreads();
            if (tid < 64) {
                int j2 = tid >> 2, row = tid & 3;
                float4 s = {0,0,0,0};
#pragma unroll
                for (int kg = 0; kg < 32; kg++) {
                    float4 v = P4[row*516 + kg*16 + j2];
                    s.x += v.x; s.y += v.y; s.z += v.z; s.w += v.w;
                }
                const float* rb1p = A.rb1 + l*512 + m*64 + j2*4;
                ((float*)&r1locT[j2*4 + 0])[row] = relu(s.x + rb1p[0]);
                ((float*)&r1locT[j2*4 + 1])[row] = relu(s.y + rb1p[1]);
                ((float*)&r1locT[j2*4 + 2])[row] = relu(s.z + rb1p[2]);
                ((float*)&r1locT[j2*4 + 3])[row] = relu(s.w + rb1p[3]);
            }
            __syncthreads();

            // ---- MV3: r2 K-slice (rows m*64..m*64+63, all 64 f4-cols).
            //      Uses ONLY local r1 slice -> no barrier before it.
            {
                int j = tid & 63, kg = tid >> 6;
                const float4* Wq = (const float4*)A.r2w + (size_t)l*512*64
                                   + (size_t)(m*64) * 64 + j;
                float4 a0={0,0,0,0}, a1v={0,0,0,0}, a2={0,0,0,0}, a3={0,0,0,0};
                int k0 = kg * 8;
#pragma unroll
                for (int kk = 0; kk < 8; kk++) {
                    int lk = k0 + kk;
                    fma16(Wq[(size_t)lk * 64], r1locT[lk], a0, a1v, a2, a3);
                }
                int b = kg*64 + j;
                P4[b] = a0; P4[516 + b] = a1v; P4[2*516 + b] = a2; P4[3*516 + b] = a3;
            }
            __syncthreads();
            {
                int j2 = tid >> 2, row = tid & 3;
                if (tid < 256) {
                    float4 s = {0,0,0,0};
#pragma unroll
                    for (int kg = 0; kg < 8; kg++) {
                        float4 v = P4[row*516 + kg*64 + j2];
                        s.x += v.x; s.y += v.y; s.z += v.z; s.w += v.w;
                    }
                    float* d = r2P + m*1024 + row*256 + j2*4;
                    cst(d+0, s.x); cst(d+1, s.y); cst(d+2, s.z); cst(d+3, s.w);
                }
            }
            csig(); cwait();   // B2: r2 partials visible

            // ---- phase C (redundant): x = LN(sum r2 partials + rb2 + h) + res ----
            const float* rb2p = A.rb2 + l*HH;
            float s0 = rb2p[n] + h2[l][0];
            float s1 = rb2p[n] + h2[l][1];
#pragma unroll
            for (int mm = 0; mm < SWG; mm++) {
                s0 += cld(r2P + mm*1024 + rA*256 + n);
                s1 += cld(r2P + mm*1024 + rB*256 + n);
            }
            rs = rowsum4(s0, s0*s0, s1, s1*s1, scr, tid);
            {
                const float* g = A.rln_g + l*HH; const float* b = A.rln_b + l*HH;
                float mu = rs.x*(1.f/HH), inv = rsqrtf(rs.y*(1.f/HH) - mu*mu + LN_EPS);
                x2[0] = (s0 - mu) * inv * g[n] + b[n] + x2[0];
                mu = rs.z*(1.f/HH); inv = rsqrtf(rs.w*(1.f/HH) - mu*mu + LN_EPS);
                x2[1] = (s1 - mu) * inv * g[n] + b[n] + x2[1];
            }
        }   // layers

        // ---- head: o1 N-slice (K=384, 4 f4-cols). KG=128, PL=516 ----
        ((float*)&xT4[n])[rA] = x2[0];
        ((float*)&xT4[n])[rB] = x2[1];
        __syncthreads();
        {
            int j = tid & 3, kg = tid >> 2;
            const float4* Wq = (const float4*)A.o1w + (m*4 + j);
            float4 a0={0,0,0,0}, a1v={0,0,0,0}, a2={0,0,0,0}, a3={0,0,0,0};
            int k0 = kg * 3;
#pragma unroll
            for (int kk = 0; kk < 3; kk++) {
                int k = k0 + kk;
                float4 x = (k < 256) ? xT4[k] : skT4[k - 256];
                fma16(Wq[(size_t)k * 32], x, a0, a1v, a2, a3);
            }
            int b = kg*4 + j;
            P4[b] = a0; P4[516 + b] = a1v; P4[2*516 + b] = a2; P4[3*516 + b] = a3;
        }
        __syncthreads();
        float* o1S = o1B + (t & 1) * 512;
        if (tid < 16) {
            int j2 = tid >> 2, row = tid & 3;
            float4 s = {0,0,0,0};
#pragma unroll
            for (int kg = 0; kg < 128; kg++) {
                float4 v = P4[row*516 + kg*4 + j2];
                s.x += v.x; s.y += v.y; s.z += v.z; s.w += v.w;
            }
            float* d = o1S + row*128 + m*16 + j2*4;
            cst(d+0, s.x); cst(d+1, s.y); cst(d+2, s.z); cst(d+3, s.w);
        }
        csig();            // head partials signaled by all members
        if (m == 0) {
            cwait();       // only m0 consumes o1
            int mm = tid & 127, row = tid >> 7;
            float v = cld(o1S + row*128 + mm) + A.ob1[mm];
            float2 f2 = red2head(v, v * v, scr, tid);
            float mu = f2.x * (1.f/128.f);
            float inv = rsqrtf(f2.y * (1.f/128.f) - mu*mu + LN_EPS);
            float contrib = relu((v - mu) * inv * A.oln_g[mm] + A.oln_b[mm]) * A.ow2[mm];
            f2 = red2head(contrib, 0.f, scr, tid);
            if (mm == 0) A.out[(RW*cid + row) * TT + t] = f2.x + A.ob2[0];
        }
        __syncthreads();   // protect LDS for next step
    }
}

// ---------------- launch ----------------

extern "C" void kernel_launch(void* const* d_in, const int* in_sizes, int n_in,
                              void* d_out, int out_size, void* d_ws, size_t ws_size,
                              hipStream_t stream) {
    // zero per-member flag region (32 clusters x 128 ints)
    hipMemsetAsync(d_ws, 0, CLN * 128 * sizeof(int), stream);

    Args A;
    A.params     = (const float*)d_in[0];
    A.disp       = (const float*)d_in[1];
    A.ew         = (const float*)d_in[2];
    A.embed_b    = (const float*)d_in[3];
    A.embed_g    = (const float*)d_in[4];
    A.embed_beta = (const float*)d_in[5];
    A.sw         = (const float*)d_in[6];
    A.skip_b     = (const float*)d_in[7];
    A.gw         = (const float*)d_in[8];
    A.gates_b    = (const float*)d_in[9];
    A.inln_g     = (const float*)d_in[10];
    A.inln_b     = (const float*)d_in[11];
    A.hln_g      = (const float*)d_in[12];
    A.hln_b      = (const float*)d_in[13];
    A.sln_g      = (const float*)d_in[14];
    A.sln_b      = (const float*)d_in[15];
    A.a1w        = (const float*)d_in[16];
    A.ab1        = (const float*)d_in[17];
    A.aw2        = (const float*)d_in[18];
    A.ab2        = (const float*)d_in[19];
    A.r1w        = (const float*)d_in[20];
    A.rb1        = (const float*)d_in[21];
    A.r2w        = (const float*)d_in[22];
    A.rb2        = (const float*)d_in[23];
    A.rln_g      = (const float*)d_in[24];
    A.rln_b      = (const float*)d_in[25];
    A.o1w        = (const float*)d_in[26];
    A.ob1        = (const float*)d_in[27];
    A.oln_g      = (const float*)d_in[28];
    A.oln_b      = (const float*)d_in[29];
    A.ow2        = (const float*)d_in[30];
    A.ob2        = (const float*)d_in[31];
    A.out        = (float*)d_out;
    A.bar        = (int*)d_ws;
    A.act        = (float*)d_ws + CLN * 128;

    xlstm_kernel<<<CLN * SWG, NTH, 0, stream>>>(A);
}